// Round 11
// baseline (633.568 us; speedup 1.0000x reference)
//
#include <hip/hip_runtime.h>
#include <math.h>

// Problem constants (MixtureLowRankRNN)
#define HIDDEN_ 1024
#define RANK_ 4
#define INPUT_ 16
#define T_ 1024
#define BATCH_ 32

// single-wave scan geometry
#define SW_ 64                     // one wave per batch
#define EPT1_ (HIDDEN_ / SW_)      // 16 h-elements per lane

// precompute geometry
#define PRE_TPB_ 256
#define PRE_BLOCKS_ 2048
#define ROWS_ (BATCH_ * T_)
#define PASSES_ (ROWS_ / PRE_BLOCKS_)

// fused fallback geometry (R8, proven 468us)
#define NT_ 512
#define SCANT_ 256
#define EPT_ 4
#define CH_ 64
#define NCH_ (T_ / CH_)

__device__ __forceinline__ float fast_exp2(float x) {
#if defined(__has_builtin)
#if __has_builtin(__builtin_amdgcn_exp2f)
    return __builtin_amdgcn_exp2f(x);
#else
    return exp2f(x);
#endif
#else
    return exp2f(x);
#endif
}

__device__ __forceinline__ float fast_rcp(float x) {
#if defined(__has_builtin)
#if __has_builtin(__builtin_amdgcn_rcpf)
    return __builtin_amdgcn_rcpf(x);
#else
    return 1.0f / x;
#endif
#else
    return 1.0f / x;
#endif
}

// tanh(x) = 1 - 2/(exp(2x)+1); exp(2x) = 2^(2*log2(e)*x).
__device__ __forceinline__ float tanh_fast(float x) {
    float e = fast_exp2(x * 2.885390081777926815f); // 2*log2(e)
    return fmaf(-2.0f, fast_rcp(e + 1.0f), 1.0f);
}

// One DPP reduce step: v += dpp_mov(v, ctrl) with old=0, bound_ctrl=1
#define DPP_ADD(v, ctrl)                                                          \
    do {                                                                          \
        int _t = __builtin_amdgcn_update_dpp(0, __float_as_int(v), (ctrl), 0xf,   \
                                             0xf, true);                          \
        (v) += __int_as_float(_t);                                                \
    } while (0)

__device__ __forceinline__ float readlane63(float v) {
    return __int_as_float(__builtin_amdgcn_readlane(__float_as_int(v), 63));
}

// ---------------------------------------------------------------------------
// Kernel 1: u[row, h] = kin * sum_i I[h,i] * x[row,i]   (row = b*T + t)
// ---------------------------------------------------------------------------
__global__ __launch_bounds__(PRE_TPB_, 2) void precompute_u(
    const float* __restrict__ x,     // [ROWS_, 16]
    const float* __restrict__ imat,  // [H, 16]
    float* __restrict__ u)           // [ROWS_, H]
{
    const int tid = threadIdx.x;
    const int bid = blockIdx.x;
    const float kin = 0.1f;

    float Ir[4][INPUT_];
#pragma unroll
    for (int r = 0; r < 4; ++r) {
        const float* ip = imat + (4 * tid + r) * INPUT_;
#pragma unroll
        for (int q = 0; q < 4; ++q) {
            const float4 v = *(const float4*)(ip + 4 * q);
            Ir[r][q*4+0] = kin * v.x; Ir[r][q*4+1] = kin * v.y;
            Ir[r][q*4+2] = kin * v.z; Ir[r][q*4+3] = kin * v.w;
        }
    }

    for (int p = 0; p < PASSES_; ++p) {
        const int row = p * PRE_BLOCKS_ + bid;
        const float* xr = x + (size_t)row * INPUT_;
        float xv[INPUT_];
#pragma unroll
        for (int q = 0; q < 4; ++q) {
            const float4 v = ((const float4*)xr)[q];
            xv[q*4+0] = v.x; xv[q*4+1] = v.y; xv[q*4+2] = v.z; xv[q*4+3] = v.w;
        }
        float a[4];
#pragma unroll
        for (int r = 0; r < 4; ++r) {
            float s0 = xv[0] * Ir[r][0];
            float s1 = xv[1] * Ir[r][1];
#pragma unroll
            for (int i = 2; i < INPUT_; i += 2) {
                s0 = fmaf(xv[i],     Ir[r][i],     s0);
                s1 = fmaf(xv[i + 1], Ir[r][i + 1], s1);
            }
            a[r] = s0 + s1;
        }
        float4 acc = make_float4(a[0], a[1], a[2], a[3]);
        *(float4*)(u + (size_t)row * HIDDEN_ + 4 * tid) = acc;  // coalesced
    }
}

// ---------------------------------------------------------------------------
// Kernel 2: BARRIERLESS single-wave scan. One wave per batch, EPT=16.
// No LDS, no s_barrier in the T-loop: the cross-lane reduce is the proven
// DPP chain -> lane 63, broadcast via v_readlane (SGPR). u prefetched in a
// depth-4 register ring, loop unrolled x4 so ring indices are static
// (rule #20). y stored fire-and-forget by lanes 0-19.
//   s_t = n^T tanh(h_{t-1});  h_t = kd*h + (krec*m)s_t + u_t;
//   y_t = kd*y + [krec*s_t ; kin*x_t]
// ---------------------------------------------------------------------------
__global__ __launch_bounds__(SW_)
__attribute__((amdgpu_waves_per_eu(1, 1)))
void rnn_scan1w(
    const float* __restrict__ x,     // [B, T, 16]
    const float* __restrict__ m,     // [H, 4]
    const float* __restrict__ n,     // [H, 4]
    const float* __restrict__ u,     // [B, T, H] precomputed
    float* __restrict__ out)         // [B, T, 20]
{
    const int lane = threadIdx.x;
    const int b    = blockIdx.x;

    const float kd   = 0.9f;
    const float krec = 0.1f * (500.0f / 1024.0f);
    const float kin  = 0.1f;

    float h[EPT1_];
    float mrs[EPT1_][RANK_];
    float nr[EPT1_][RANK_];
#pragma unroll
    for (int j = 0; j < EPT1_; ++j) {
        const int hidx = lane * EPT1_ + j;
        h[j] = 0.0f;
        const float4 mv = *(const float4*)(m + hidx * RANK_);
        mrs[j][0] = krec * mv.x; mrs[j][1] = krec * mv.y;
        mrs[j][2] = krec * mv.z; mrs[j][3] = krec * mv.w;
        const float4 nv = *(const float4*)(n + hidx * RANK_);
        nr[j][0] = nv.x; nr[j][1] = nv.y; nr[j][2] = nv.z; nr[j][3] = nv.w;
    }

    const float* xb = x + (size_t)b * T_ * INPUT_;
    const float* ub = u + (size_t)b * T_ * HIDDEN_ + lane * EPT1_;
    float* ob = out + (size_t)b * T_ * (RANK_ + INPUT_);

    const int xoff = (lane >= 4 && lane < 20) ? (lane - 4) : 0;

    // depth-4 u ring (4 x 4 float4 = 64 VGPR) + x ring
    float4 upf[4][4];
    float xpf[4];
#pragma unroll
    for (int k = 0; k < 4; ++k) {
        const float* up = ub + (size_t)k * HIDDEN_;
        upf[k][0] = *(const float4*)(up);
        upf[k][1] = *(const float4*)(up + 4);
        upf[k][2] = *(const float4*)(up + 8);
        upf[k][3] = *(const float4*)(up + 12);
        xpf[k] = xb[k * INPUT_ + xoff];
    }

    float y = 0.0f;

#define SW_STEP(k)                                                               \
    {                                                                            \
        const int t = tb + (k);                                                  \
        /* pull ring slot into locals, then refill (loads issue early) */        \
        const float4 u0 = upf[k][0], u1 = upf[k][1];                             \
        const float4 u2 = upf[k][2], u3 = upf[k][3];                             \
        const float xcur = xpf[k];                                               \
        {                                                                        \
            int tn = t + 4; if (tn >= T_) tn = T_ - 1;                           \
            const float* up = ub + (size_t)tn * HIDDEN_;                         \
            upf[k][0] = *(const float4*)(up);                                    \
            upf[k][1] = *(const float4*)(up + 4);                                \
            upf[k][2] = *(const float4*)(up + 8);                                \
            upf[k][3] = *(const float4*)(up + 12);                               \
            xpf[k] = xb[tn * INPUT_ + xoff];                                     \
        }                                                                        \
        /* tanh */                                                               \
        float th[EPT1_];                                                         \
        _Pragma("unroll")                                                        \
        for (int j = 0; j < EPT1_; ++j) th[j] = tanh_fast(h[j]);                 \
        /* rank partials: 2 chains per rank */                                   \
        float p[RANK_], q[RANK_];                                                \
        _Pragma("unroll")                                                        \
        for (int r = 0; r < RANK_; ++r) {                                        \
            p[r] = th[0] * nr[0][r];                                             \
            q[r] = th[1] * nr[1][r];                                             \
        }                                                                        \
        _Pragma("unroll")                                                        \
        for (int j = 2; j < EPT1_; j += 2) {                                     \
            _Pragma("unroll")                                                    \
            for (int r = 0; r < RANK_; ++r) {                                    \
                p[r] = fmaf(th[j],     nr[j][r],     p[r]);                      \
                q[r] = fmaf(th[j + 1], nr[j + 1][r], q[r]);                      \
            }                                                                    \
        }                                                                        \
        _Pragma("unroll")                                                        \
        for (int r = 0; r < RANK_; ++r) p[r] += q[r];                            \
        /* wave reduce via DPP to lane 63, level-major */                        \
        DPP_ADD(p[0], 0x111); DPP_ADD(p[1], 0x111); DPP_ADD(p[2], 0x111); DPP_ADD(p[3], 0x111); \
        DPP_ADD(p[0], 0x112); DPP_ADD(p[1], 0x112); DPP_ADD(p[2], 0x112); DPP_ADD(p[3], 0x112); \
        DPP_ADD(p[0], 0x114); DPP_ADD(p[1], 0x114); DPP_ADD(p[2], 0x114); DPP_ADD(p[3], 0x114); \
        DPP_ADD(p[0], 0x118); DPP_ADD(p[1], 0x118); DPP_ADD(p[2], 0x118); DPP_ADD(p[3], 0x118); \
        DPP_ADD(p[0], 0x142); DPP_ADD(p[1], 0x142); DPP_ADD(p[2], 0x142); DPP_ADD(p[3], 0x142); \
        DPP_ADD(p[0], 0x143); DPP_ADD(p[1], 0x143); DPP_ADD(p[2], 0x143); DPP_ADD(p[3], 0x143); \
        /* broadcast via readlane (SGPR) — no LDS, no barrier */                 \
        const float s0 = readlane63(p[0]);                                       \
        const float s1 = readlane63(p[1]);                                       \
        const float s2 = readlane63(p[2]);                                       \
        const float s3 = readlane63(p[3]);                                       \
        /* h <- kd*h + mrs@s + u */                                              \
        const float uq[EPT1_] = {u0.x, u0.y, u0.z, u0.w, u1.x, u1.y, u1.z, u1.w, \
                                 u2.x, u2.y, u2.z, u2.w, u3.x, u3.y, u3.z, u3.w};\
        _Pragma("unroll")                                                        \
        for (int j = 0; j < EPT1_; ++j) {                                        \
            float a = fmaf(s0, mrs[j][0], uq[j]);                                \
            a = fmaf(s1, mrs[j][1], a);                                          \
            a = fmaf(s2, mrs[j][2], a);                                          \
            a = fmaf(s3, mrs[j][3], a);                                          \
            h[j] = fmaf(kd, h[j], a);                                            \
        }                                                                        \
        /* y (lanes 0-19), fire-and-forget store */                              \
        if (lane < 20) {                                                         \
            float drive;                                                         \
            if (lane < 4) {                                                      \
                const float sv = (lane == 0) ? s0 : (lane == 1) ? s1             \
                               : (lane == 2) ? s2 : s3;                          \
                drive = krec * sv;                                               \
            } else {                                                             \
                drive = kin * xcur;                                              \
            }                                                                    \
            y = fmaf(kd, y, drive);                                              \
            ob[t * 20 + lane] = y;                                               \
        }                                                                        \
    }

    for (int tb = 0; tb < T_; tb += 4) {
        SW_STEP(0)
        SW_STEP(1)
        SW_STEP(2)
        SW_STEP(3)
    }
#undef SW_STEP
}

// ---------------------------------------------------------------------------
// Fallback (no workspace): R8 fused kernel (proven 468us), verbatim.
// ---------------------------------------------------------------------------
__global__ __launch_bounds__(NT_)
__attribute__((amdgpu_waves_per_eu(2, 2)))
void rnn_fused_kernel(
    const float* __restrict__ x, const float* __restrict__ m,
    const float* __restrict__ n, const float* __restrict__ imat,
    float* __restrict__ out)
{
    const int tid  = threadIdx.x;
    const int lane = tid & 63;
    const int b    = blockIdx.x;
    const bool is_scan = (tid < SCANT_);

    const float kd   = 0.9f;
    const float krec = 0.1f * (500.0f / 1024.0f);
    const float kin  = 0.1f;

    __shared__ float4 part[2][SCANT_ / 64];
    __shared__ float  axs[4][HIDDEN_];
    __shared__ float  xs[2][CH_ * INPUT_];

    const float* xb = x + (size_t)b * T_ * INPUT_;
    float* ob = out + (size_t)b * T_ * (RANK_ + INPUT_);

    float h[EPT_];
    float mrs[EPT_][RANK_];
    float nr[EPT_][RANK_];
    float Irs[EPT_][INPUT_];
    float4 xstage = make_float4(0.f, 0.f, 0.f, 0.f);
    float y = 0.0f;
    int yoff = 0;

    if (is_scan) {
#pragma unroll
        for (int j = 0; j < EPT_; ++j) {
            const int hidx = tid * EPT_ + j;
            h[j] = 0.0f;
            const float4 mv = *(const float4*)(m + hidx * RANK_);
            mrs[j][0] = krec * mv.x; mrs[j][1] = krec * mv.y;
            mrs[j][2] = krec * mv.z; mrs[j][3] = krec * mv.w;
            const float4 nv = *(const float4*)(n + hidx * RANK_);
            nr[j][0] = nv.x; nr[j][1] = nv.y; nr[j][2] = nv.z; nr[j][3] = nv.w;
        }
    } else {
        const int tH = tid - SCANT_;
        yoff = (tH >= 4 && tH < 20) ? (tH - 4) : 0;
#pragma unroll
        for (int j = 0; j < EPT_; ++j) {
            const int hidx = tH * EPT_ + j;
#pragma unroll
            for (int q = 0; q < 4; ++q) {
                const float4 iv = *(const float4*)(imat + hidx * INPUT_ + q * 4);
                Irs[j][q*4+0] = kin * iv.x; Irs[j][q*4+1] = kin * iv.y;
                Irs[j][q*4+2] = kin * iv.z; Irs[j][q*4+3] = kin * iv.w;
            }
        }
        float4 c0 = *(const float4*)(xb + tH * 4);
        *(float4*)&xs[0][tH * 4] = c0;
        xstage = *(const float4*)(xb + CH_ * INPUT_ + tH * 4);
        float xv[INPUT_];
#pragma unroll
        for (int q = 0; q < 4; ++q) {
            const float4 v = ((const float4*)xb)[q];
            xv[q*4+0] = v.x; xv[q*4+1] = v.y; xv[q*4+2] = v.z; xv[q*4+3] = v.w;
        }
        float av[EPT_];
#pragma unroll
        for (int j = 0; j < EPT_; ++j) {
            float a = xv[0] * Irs[j][0];
            float c = xv[1] * Irs[j][1];
#pragma unroll
            for (int i = 2; i < INPUT_; i += 2) {
                a = fmaf(xv[i],     Irs[j][i],     a);
                c = fmaf(xv[i + 1], Irs[j][i + 1], c);
            }
            av[j] = a + c;
        }
        *(float4*)&axs[0][tH * 4] = make_float4(av[0], av[1], av[2], av[3]);
    }
    __syncthreads();

    for (int t = 0; t < T_; ++t) {
        if (is_scan) {
            float th[EPT_];
#pragma unroll
            for (int j = 0; j < EPT_; ++j) th[j] = tanh_fast(h[j]);
            float p0 = th[0] * nr[0][0], p1 = th[0] * nr[0][1];
            float p2 = th[0] * nr[0][2], p3 = th[0] * nr[0][3];
#pragma unroll
            for (int j = 1; j < EPT_; ++j) {
                p0 = fmaf(th[j], nr[j][0], p0);
                p1 = fmaf(th[j], nr[j][1], p1);
                p2 = fmaf(th[j], nr[j][2], p2);
                p3 = fmaf(th[j], nr[j][3], p3);
            }
            DPP_ADD(p0, 0x111); DPP_ADD(p1, 0x111); DPP_ADD(p2, 0x111); DPP_ADD(p3, 0x111);
            DPP_ADD(p0, 0x112); DPP_ADD(p1, 0x112); DPP_ADD(p2, 0x112); DPP_ADD(p3, 0x112);
            DPP_ADD(p0, 0x114); DPP_ADD(p1, 0x114); DPP_ADD(p2, 0x114); DPP_ADD(p3, 0x114);
            DPP_ADD(p0, 0x118); DPP_ADD(p1, 0x118); DPP_ADD(p2, 0x118); DPP_ADD(p3, 0x118);
            DPP_ADD(p0, 0x142); DPP_ADD(p1, 0x142); DPP_ADD(p2, 0x142); DPP_ADD(p3, 0x142);
            DPP_ADD(p0, 0x143); DPP_ADD(p1, 0x143); DPP_ADD(p2, 0x143); DPP_ADD(p3, 0x143);
            if (lane == 63) part[t & 1][tid >> 6] = make_float4(p0, p1, p2, p3);
        } else {
            const int tH = tid - SCANT_;
            const int tn = (t + 1 < T_) ? (t + 1) : (T_ - 1);
            const float* xsp = &xs[(tn >> 6) & 1][(tn & 63) * INPUT_];
            const float4 xa  = ((const float4*)xsp)[0];
            const float4 xb4 = ((const float4*)xsp)[1];
            const float4 xc  = ((const float4*)xsp)[2];
            const float4 xd  = ((const float4*)xsp)[3];
            float av[EPT_];
#pragma unroll
            for (int j = 0; j < EPT_; ++j) {
                float a = xa.x * Irs[j][0];
                float c = xa.y * Irs[j][1];
                a = fmaf(xa.z,  Irs[j][2],  a);  c = fmaf(xa.w,  Irs[j][3],  c);
                a = fmaf(xb4.x, Irs[j][4],  a);  c = fmaf(xb4.y, Irs[j][5],  c);
                a = fmaf(xb4.z, Irs[j][6],  a);  c = fmaf(xb4.w, Irs[j][7],  c);
                a = fmaf(xc.x,  Irs[j][8],  a);  c = fmaf(xc.y,  Irs[j][9],  c);
                a = fmaf(xc.z,  Irs[j][10], a);  c = fmaf(xc.w,  Irs[j][11], c);
                a = fmaf(xd.x,  Irs[j][12], a);  c = fmaf(xd.y,  Irs[j][13], c);
                a = fmaf(xd.z,  Irs[j][14], a);  c = fmaf(xd.w,  Irs[j][15], c);
                av[j] = a + c;
            }
            *(float4*)&axs[(t + 1) & 3][tH * 4] =
                make_float4(av[0], av[1], av[2], av[3]);
        }

        asm volatile("s_waitcnt lgkmcnt(0)\n\ts_barrier" ::: "memory");

        if (is_scan) {
            const float4 q0 = part[t & 1][0];
            const float4 q1 = part[t & 1][1];
            const float4 q2 = part[t & 1][2];
            const float4 q3 = part[t & 1][3];
            const float4 axv = *(const float4*)&axs[t & 3][tid * 4];
            const float4 sv = (q0 + q1) + (q2 + q3);
            const float s0 = sv.x, s1 = sv.y, s2 = sv.z, s3 = sv.w;
            const float aq[EPT_] = {axv.x, axv.y, axv.z, axv.w};
#pragma unroll
            for (int j = 0; j < EPT_; ++j) {
                float a01 = fmaf(s1, mrs[j][1], fmaf(s0, mrs[j][0], aq[j]));
                float a23 = fmaf(s3, mrs[j][3], s2 * mrs[j][2]);
                h[j] = fmaf(kd, h[j], a01 + a23);
            }
        } else {
            const int tH = tid - SCANT_;
            if ((t & (CH_ - 1)) == 0) {
                const int c = t >> 6;
                *(float4*)&xs[(c + 1) & 1][tH * 4] = xstage;
                const int cl = (c + 2 < NCH_) ? (c + 2) : (NCH_ - 1);
                xstage = *(const float4*)(xb + cl * CH_ * INPUT_ + tH * 4);
            }
            if (tH < 20) {
                const float4 q0 = part[t & 1][0];
                const float4 q1 = part[t & 1][1];
                const float4 q2 = part[t & 1][2];
                const float4 q3 = part[t & 1][3];
                const float4 sv = (q0 + q1) + (q2 + q3);
                float drive;
                if (tH < 4) {
                    const float svv = (tH == 0) ? sv.x : (tH == 1) ? sv.y
                                    : (tH == 2) ? sv.z : sv.w;
                    drive = krec * svv;
                } else {
                    drive = kin * xs[(t >> 6) & 1][(t & 63) * INPUT_ + yoff];
                }
                y = fmaf(kd, y, drive);
                ob[t * 20 + tH] = y;
            }
        }
    }
}

extern "C" void kernel_launch(void* const* d_in, const int* in_sizes, int n_in,
                              void* d_out, int out_size, void* d_ws, size_t ws_size,
                              hipStream_t stream) {
    const float* x    = (const float*)d_in[0];
    const float* m    = (const float*)d_in[1];
    const float* n    = (const float*)d_in[2];
    const float* imat = (const float*)d_in[3];
    float* out = (float*)d_out;

    const size_t u_bytes = (size_t)BATCH_ * T_ * HIDDEN_ * sizeof(float); // 128 MB
    if (d_ws != nullptr && ws_size >= u_bytes) {
        float* u = (float*)d_ws;
        precompute_u<<<dim3(PRE_BLOCKS_), dim3(PRE_TPB_), 0, stream>>>(x, imat, u);
        rnn_scan1w<<<dim3(BATCH_), dim3(SW_), 0, stream>>>(x, m, n, u, out);
    } else {
        rnn_fused_kernel<<<dim3(BATCH_), dim3(NT_), 0, stream>>>(x, m, n, imat, out);
    }
}

// Round 12
// 517.757 us; speedup vs baseline: 1.2237x; 1.2237x over previous
//
#include <hip/hip_runtime.h>
#include <math.h>

// Problem constants (MixtureLowRankRNN)
#define HIDDEN_ 1024
#define RANK_ 4
#define INPUT_ 16
#define T_ 1024
#define BATCH_ 32

// Fused geometry: 512 threads = 8 waves.
//   waves 0-3 (tid 0-255)  : scan group, EPT=4 h-elements/thread
//   waves 4-7 (tid 256-511): helper group, computes ax(t+1)=kin*I@x(t+1),
//                            x staging, y output
// Wave i -> SIMD i&3, so each SIMD hosts exactly one scan + one helper wave;
// helper issue fills the scan wave's barrier/LDS-latency stalls.
//
// SESSION VERDICT (R0-R11): ~460 ns/step is the measured floor across every
// structural variant — {scratch-free, 1/2 waves per SIMD, zero in-loop VMEM,
// pk-packed, clock-loaded, barrierless}. This configuration (R8) is the best
// measured: 468us kernel / 519.6us total. Restored verbatim.
#define NT_ 512
#define SCANT_ 256
#define EPT_ 4
#define CH_ 64                  // x-steps per staged chunk (4KB)
#define NCH_ (T_ / CH_)         // 16 chunks

__device__ __forceinline__ float fast_exp2(float x) {
#if defined(__has_builtin)
#if __has_builtin(__builtin_amdgcn_exp2f)
    return __builtin_amdgcn_exp2f(x);
#else
    return exp2f(x);
#endif
#else
    return exp2f(x);
#endif
}

__device__ __forceinline__ float fast_rcp(float x) {
#if defined(__has_builtin)
#if __has_builtin(__builtin_amdgcn_rcpf)
    return __builtin_amdgcn_rcpf(x);
#else
    return 1.0f / x;
#endif
#else
    return 1.0f / x;
#endif
}

// tanh(x) = 1 - 2/(exp(2x)+1); exp(2x) = 2^(2*log2(e)*x).
__device__ __forceinline__ float tanh_fast(float x) {
    float e = fast_exp2(x * 2.885390081777926815f); // 2*log2(e)
    return fmaf(-2.0f, fast_rcp(e + 1.0f), 1.0f);
}

// One DPP reduce step: v += dpp_mov(v, ctrl) with old=0, bound_ctrl=1
#define DPP_ADD(v, ctrl)                                                          \
    do {                                                                          \
        int _t = __builtin_amdgcn_update_dpp(0, __float_as_int(v), (ctrl), 0xf,   \
                                             0xf, true);                          \
        (v) += __int_as_float(_t);                                                \
    } while (0)

// ---------------------------------------------------------------------------
// Single fused kernel. One batch per block.
//   s_t = n^T tanh(h_{t-1})                        (scan waves, DPP+LDS reduce)
//   h_t = kd*h_{t-1} + (krec*m) s_t + ax_t          (scan waves)
//   ax_t = kin * I @ x_t                            (helper waves, 1 step ahead,
//                                                    depth-4 LDS ring)
//   y_t = kd*y_{t-1} + [krec*s_t ; kin*x_t]         (helper wave 4, lanes 0-19)
//
// axs ring depth 4: read(slot k, iter k post-barrier) vs next write(slot k,
// iter k+3 pre-barrier) has >=2 barriers between -> race-free.
// ---------------------------------------------------------------------------
__global__ __launch_bounds__(NT_)
__attribute__((amdgpu_waves_per_eu(2, 2)))
void rnn_fused_kernel(
    const float* __restrict__ x,     // [B, T, 16]
    const float* __restrict__ m,     // [H, 4]
    const float* __restrict__ n,     // [H, 4]
    const float* __restrict__ imat,  // [H, 16]
    float* __restrict__ out)         // [B, T, 20]
{
    const int tid  = threadIdx.x;
    const int lane = tid & 63;
    const int b    = blockIdx.x;
    const bool is_scan = (tid < SCANT_);

    const float kd   = 0.9f;                      // 1 - ALPHA
    const float krec = 0.1f * (500.0f / 1024.0f); // ALPHA * BASE_SCALE / HIDDEN
    const float kin  = 0.1f;                      // ALPHA

    __shared__ float4 part[2][SCANT_ / 64];   // 128 B  (4 wave partials, parity)
    __shared__ float  axs[4][HIDDEN_];        // 16 KB  (ax ring, depth 4)
    __shared__ float  xs[2][CH_ * INPUT_];    // 8 KB   (x chunks, parity)

    const float* xb = x + (size_t)b * T_ * INPUT_;
    float* ob = out + (size_t)b * T_ * (RANK_ + INPUT_);

    // scan-group state
    float h[EPT_];
    float mrs[EPT_][RANK_];    // krec * m row
    float nr[EPT_][RANK_];
    // helper-group state
    float Irs[EPT_][INPUT_];   // kin * I row
    float4 xstage = make_float4(0.f, 0.f, 0.f, 0.f);
    float y = 0.0f;
    int yoff = 0;

    if (is_scan) {
#pragma unroll
        for (int j = 0; j < EPT_; ++j) {
            const int hidx = tid * EPT_ + j;
            h[j] = 0.0f;
            const float4 mv = *(const float4*)(m + hidx * RANK_);
            mrs[j][0] = krec * mv.x; mrs[j][1] = krec * mv.y;
            mrs[j][2] = krec * mv.z; mrs[j][3] = krec * mv.w;
            const float4 nv = *(const float4*)(n + hidx * RANK_);
            nr[j][0] = nv.x; nr[j][1] = nv.y; nr[j][2] = nv.z; nr[j][3] = nv.w;
        }
    } else {
        const int tH = tid - SCANT_;
        yoff = (tH >= 4 && tH < 20) ? (tH - 4) : 0;
#pragma unroll
        for (int j = 0; j < EPT_; ++j) {
            const int hidx = tH * EPT_ + j;
#pragma unroll
            for (int q = 0; q < 4; ++q) {
                const float4 iv = *(const float4*)(imat + hidx * INPUT_ + q * 4);
                Irs[j][q*4+0] = kin * iv.x; Irs[j][q*4+1] = kin * iv.y;
                Irs[j][q*4+2] = kin * iv.z; Irs[j][q*4+3] = kin * iv.w;
            }
        }
        // x chunk 0 -> xs[0]; chunk 1 -> regs (256 helper thr x float4 = 4KB)
        float4 c0 = *(const float4*)(xb + tH * 4);
        *(float4*)&xs[0][tH * 4] = c0;
        xstage = *(const float4*)(xb + CH_ * INPUT_ + tH * 4);
        // ax(0) -> axs[0] (x(0) read straight from global, wave-uniform)
        float xv[INPUT_];
#pragma unroll
        for (int q = 0; q < 4; ++q) {
            const float4 v = ((const float4*)xb)[q];
            xv[q*4+0] = v.x; xv[q*4+1] = v.y; xv[q*4+2] = v.z; xv[q*4+3] = v.w;
        }
        float av[EPT_];
#pragma unroll
        for (int j = 0; j < EPT_; ++j) {
            float a = xv[0] * Irs[j][0];
            float c = xv[1] * Irs[j][1];
#pragma unroll
            for (int i = 2; i < INPUT_; i += 2) {
                a = fmaf(xv[i],     Irs[j][i],     a);
                c = fmaf(xv[i + 1], Irs[j][i + 1], c);
            }
            av[j] = a + c;
        }
        *(float4*)&axs[0][tH * 4] = make_float4(av[0], av[1], av[2], av[3]);
    }
    __syncthreads();   // xs[0]/axs[0] visible to everyone

    for (int t = 0; t < T_; ++t) {
        // ================= pre-barrier phase =================
        if (is_scan) {
            // tanh(h) + rank partials
            float th[EPT_];
#pragma unroll
            for (int j = 0; j < EPT_; ++j) th[j] = tanh_fast(h[j]);

            float p0 = th[0] * nr[0][0], p1 = th[0] * nr[0][1];
            float p2 = th[0] * nr[0][2], p3 = th[0] * nr[0][3];
#pragma unroll
            for (int j = 1; j < EPT_; ++j) {
                p0 = fmaf(th[j], nr[j][0], p0);
                p1 = fmaf(th[j], nr[j][1], p1);
                p2 = fmaf(th[j], nr[j][2], p2);
                p3 = fmaf(th[j], nr[j][3], p3);
            }

            // wave reduce via DPP, level-major for ILP across 4 ranks
            DPP_ADD(p0, 0x111); DPP_ADD(p1, 0x111); DPP_ADD(p2, 0x111); DPP_ADD(p3, 0x111);
            DPP_ADD(p0, 0x112); DPP_ADD(p1, 0x112); DPP_ADD(p2, 0x112); DPP_ADD(p3, 0x112);
            DPP_ADD(p0, 0x114); DPP_ADD(p1, 0x114); DPP_ADD(p2, 0x114); DPP_ADD(p3, 0x114);
            DPP_ADD(p0, 0x118); DPP_ADD(p1, 0x118); DPP_ADD(p2, 0x118); DPP_ADD(p3, 0x118);
            DPP_ADD(p0, 0x142); DPP_ADD(p1, 0x142); DPP_ADD(p2, 0x142); DPP_ADD(p3, 0x142);
            DPP_ADD(p0, 0x143); DPP_ADD(p1, 0x143); DPP_ADD(p2, 0x143); DPP_ADD(p3, 0x143);

            if (lane == 63) part[t & 1][tid >> 6] = make_float4(p0, p1, p2, p3);
        } else {
            // helper: ax(t+1) from staged x, into ring slot (t+1)&3
            const int tH = tid - SCANT_;
            const int tn = (t + 1 < T_) ? (t + 1) : (T_ - 1);
            const float* xsp = &xs[(tn >> 6) & 1][(tn & 63) * INPUT_];
            const float4 xa  = ((const float4*)xsp)[0];
            const float4 xb4 = ((const float4*)xsp)[1];
            const float4 xc  = ((const float4*)xsp)[2];
            const float4 xd  = ((const float4*)xsp)[3];
            float av[EPT_];
#pragma unroll
            for (int j = 0; j < EPT_; ++j) {
                float a = xa.x * Irs[j][0];
                float c = xa.y * Irs[j][1];
                a = fmaf(xa.z,  Irs[j][2],  a);  c = fmaf(xa.w,  Irs[j][3],  c);
                a = fmaf(xb4.x, Irs[j][4],  a);  c = fmaf(xb4.y, Irs[j][5],  c);
                a = fmaf(xb4.z, Irs[j][6],  a);  c = fmaf(xb4.w, Irs[j][7],  c);
                a = fmaf(xc.x,  Irs[j][8],  a);  c = fmaf(xc.y,  Irs[j][9],  c);
                a = fmaf(xc.z,  Irs[j][10], a);  c = fmaf(xc.w,  Irs[j][11], c);
                a = fmaf(xd.x,  Irs[j][12], a);  c = fmaf(xd.y,  Irs[j][13], c);
                a = fmaf(xd.z,  Irs[j][14], a);  c = fmaf(xd.w,  Irs[j][15], c);
                av[j] = a + c;
            }
            *(float4*)&axs[(t + 1) & 3][tH * 4] =
                make_float4(av[0], av[1], av[2], av[3]);
        }

        // Raw barrier: per-wave lgkm drain + sync. No vmcnt drain — x staging
        // loads and y stores stay in flight across steps.
        asm volatile("s_waitcnt lgkmcnt(0)\n\ts_barrier" ::: "memory");

        // ================= post-barrier phase =================
        if (is_scan) {
            const float4 q0 = part[t & 1][0];
            const float4 q1 = part[t & 1][1];
            const float4 q2 = part[t & 1][2];
            const float4 q3 = part[t & 1][3];
            const float4 axv = *(const float4*)&axs[t & 3][tid * 4];

            const float4 sv = (q0 + q1) + (q2 + q3);
            const float s0 = sv.x, s1 = sv.y, s2 = sv.z, s3 = sv.w;
            const float aq[EPT_] = {axv.x, axv.y, axv.z, axv.w};
#pragma unroll
            for (int j = 0; j < EPT_; ++j) {
                float a01 = fmaf(s1, mrs[j][1], fmaf(s0, mrs[j][0], aq[j]));
                float a23 = fmaf(s3, mrs[j][3], s2 * mrs[j][2]);
                h[j] = fmaf(kd, h[j], a01 + a23);
            }
        } else {
            const int tH = tid - SCANT_;
            // x chunk staging every 64 steps (writes the buffer not in use)
            if ((t & (CH_ - 1)) == 0) {
                const int c = t >> 6;
                *(float4*)&xs[(c + 1) & 1][tH * 4] = xstage;   // chunk c+1
                const int cl = (c + 2 < NCH_) ? (c + 2) : (NCH_ - 1);
                xstage = *(const float4*)(xb + cl * CH_ * INPUT_ + tH * 4);
            }
            // y path: lanes 0-19 of helper wave 4
            if (tH < 20) {
                const float4 q0 = part[t & 1][0];
                const float4 q1 = part[t & 1][1];
                const float4 q2 = part[t & 1][2];
                const float4 q3 = part[t & 1][3];
                const float4 sv = (q0 + q1) + (q2 + q3);
                float drive;
                if (tH < 4) {
                    const float svv = (tH == 0) ? sv.x : (tH == 1) ? sv.y
                                    : (tH == 2) ? sv.z : sv.w;
                    drive = krec * svv;
                } else {
                    drive = kin * xs[(t >> 6) & 1][(t & 63) * INPUT_ + yoff];
                }
                y = fmaf(kd, y, drive);
                ob[t * 20 + tH] = y;   // fire-and-forget global store
            }
        }
    }
}

extern "C" void kernel_launch(void* const* d_in, const int* in_sizes, int n_in,
                              void* d_out, int out_size, void* d_ws, size_t ws_size,
                              hipStream_t stream) {
    const float* x    = (const float*)d_in[0];
    const float* m    = (const float*)d_in[1];
    const float* n    = (const float*)d_in[2];
    const float* imat = (const float*)d_in[3];
    float* out = (float*)d_out;

    rnn_fused_kernel<<<dim3(BATCH_), dim3(NT_), 0, stream>>>(x, m, n, imat, out);
}